// Round 5
// baseline (172.561 us; speedup 1.0000x reference)
//
#include <hip/hip_runtime.h>
#include <hip/hip_cooperative_groups.h>

namespace cg = cooperative_groups;

#define NPAIR  144
#define KLEN   512
#define GPTS   2048
#define NFRM   256
#define FPB    4                  // frames per block
#define NFG    (NFRM / FPB)       // 64 frame groups
#define GSPLIT 4                  // g splits per frame group
#define GPB    (GPTS / GSPLIT)    // 512 g per block (1 per thread)
#define NSLOT  16                 // staged lags: k in {0..7} U {504..511}
#define NJ4    (NPAIR / 4)        // 36 packed-index dwords per g
#define EPSV   1e-12f

// Single cooperative kernel: gather + per-frame normalization fused.
// 256 blocks (= 1/CU, co-resident) x 512 threads; 36 KiB LDS.
//
// XCD-locality: blocks dispatch round-robin across 8 XCDs (XCD = bi%8).
// fg = bi & 63, gs = bi >> 6 puts the 4 g-split siblings of a frame-group
// (which stage IDENTICAL x-clumps AND exchange per-frame partials) at
// bi = fg + {0,64,128,192}, all congruent mod 8 -> same XCD: staged clump
// sectors are fetched from HBM once and L2-hit 3x, and the partial
// exchange after grid.sync() stays within one coherent L2. (Correctness
// does NOT depend on this mapping: __threadfence + grid.sync provide
// device-scope visibility.)
//
// tau0 is geometrically bounded: |lag| <= 0.1m*16000/343 = 4.66, so
// tau in {0..5} U {507..511}; slot = tau & 15 is collision-free there.
// Stage 16 slots: seg0 k=0..7 -> slots 0..7, seg1 k=504..511 -> 8..15.
//
// Normalization: reference computes v' = v - mean + eps, out = v'/max(v').
// x -> x - mean + eps is monotone nondecreasing in fp, so
// max(v') = (max(v) - mean) + eps exactly; blocks only need per-frame
// (sum, max) partials -- 8 B x 4 frames -- exchanged through an 8 KB
// array, then normalize register-resident acc directly into out. This
// removes the separate norm kernel, its launch gap, and the 2 MB maps
// round-trip entirely.
__global__ __launch_bounds__(512)
void srp_fused_kernel(const float* __restrict__ x,
                      const int* __restrict__ tau0,
                      float2* __restrict__ partials,
                      float* __restrict__ out) {
    __shared__ __align__(16) float xc[NPAIR * NSLOT * FPB];   // 36864 B
    __shared__ float redS[8 * FPB];
    __shared__ float redX[8 * FPB];
    __shared__ float2 nrm[FPB];

    const int bi = blockIdx.x;
    const int fg = bi & (NFG - 1);
    const int gs = bi >> 6;
    const int t  = threadIdx.x;
    const int g  = gs * GPB + t;

    // Stage clumps: item = (pair, fr, seg), 1152 items x 32 B, ~2.25/thread.
    for (int i = t; i < NPAIR * FPB * 2; i += 512) {
        int pair = i >> 3;
        int fr   = (i >> 1) & 3;
        int seg  = i & 1;
        const float* src = x + ((size_t)(fg * FPB + fr) * NPAIR + pair) * KLEN
                             + (seg ? 504 : 0);
        int base = pair * NSLOT + seg * 8;
        #pragma unroll
        for (int jj = 0; jj < 2; ++jj) {
            float4 v = ((const float4*)src)[jj];
            xc[(base + jj * 4 + 0) * FPB + fr] = v.x;
            xc[(base + jj * 4 + 1) * FPB + fr] = v.y;
            xc[(base + jj * 4 + 2) * FPB + fr] = v.z;
            xc[(base + jj * 4 + 3) * FPB + fr] = v.w;
        }
    }

    // In-register index pack (hidden under staging-load latency + barrier):
    // dj[j4] byte b = (slot << 4) = LDS byte offset within pair's clump row.
    unsigned dj[NJ4];
    #pragma unroll
    for (int j4 = 0; j4 < NJ4; ++j4) {
        unsigned d = 0;
        #pragma unroll
        for (int b = 0; b < 4; ++b) {
            int v = tau0[(j4 * 4 + b) * GPTS + g];   // coalesced (lanes vary g)
            d |= (((unsigned)v & 15u) << 4) << (8 * b);
        }
        dj[j4] = d;
    }

    __syncthreads();

    const char* xb = (const char*)xc;
    float4 acc = {0.f, 0.f, 0.f, 0.f};
    #pragma unroll
    for (int j4 = 0; j4 < NJ4; ++j4) {
        unsigned d = dj[j4];
        #pragma unroll
        for (int b = 0; b < 4; ++b) {
            // byte addr = pair*256 + slot*16 (pair row = 16 slots x 16 B)
            unsigned off = (d >> (8 * b)) & 0xf0u;
            const float4 v = *(const float4*)(xb + (((j4 * 4 + b) << 8) + off));
            acc.x += v.x; acc.y += v.y; acc.z += v.z; acc.w += v.w;
        }
    }

    // Per-frame block partials: sum + max over this block's 512 g.
    float4 sm = acc, mx = acc;
    #pragma unroll
    for (int off = 32; off > 0; off >>= 1) {
        sm.x += __shfl_down(sm.x, off, 64);
        sm.y += __shfl_down(sm.y, off, 64);
        sm.z += __shfl_down(sm.z, off, 64);
        sm.w += __shfl_down(sm.w, off, 64);
        mx.x = fmaxf(mx.x, __shfl_down(mx.x, off, 64));
        mx.y = fmaxf(mx.y, __shfl_down(mx.y, off, 64));
        mx.z = fmaxf(mx.z, __shfl_down(mx.z, off, 64));
        mx.w = fmaxf(mx.w, __shfl_down(mx.w, off, 64));
    }
    const int wave = t >> 6, lane = t & 63;
    if (lane == 0) {
        redS[wave * 4 + 0] = sm.x; redS[wave * 4 + 1] = sm.y;
        redS[wave * 4 + 2] = sm.z; redS[wave * 4 + 3] = sm.w;
        redX[wave * 4 + 0] = mx.x; redX[wave * 4 + 1] = mx.y;
        redX[wave * 4 + 2] = mx.z; redX[wave * 4 + 3] = mx.w;
    }
    __syncthreads();
    if (t < FPB) {                       // t = frame index within group
        float S = 0.f, X = -3.402823466e38f;
        #pragma unroll
        for (int w = 0; w < 8; ++w) {
            S += redS[w * 4 + t];
            X = fmaxf(X, redX[w * 4 + t]);
        }
        partials[(fg * FPB + t) * GSPLIT + gs] = make_float2(S, X);
    }
    __threadfence();                     // release partials device-wide
    cg::this_grid().sync();

    if (t < FPB) {
        float S = 0.f, X = -3.402823466e38f;
        #pragma unroll
        for (int k = 0; k < GSPLIT; ++k) {
            float2 p = partials[(fg * FPB + t) * GSPLIT + k];
            S += p.x;
            X = fmaxf(X, p.y);
        }
        float mean = S * (1.0f / (float)GPTS);
        nrm[t] = make_float2(mean, 1.0f / ((X - mean) + EPSV));
    }
    __syncthreads();

    float* op = out + (size_t)(fg * FPB) * GPTS + g;
    op[0 * GPTS] = ((acc.x - nrm[0].x) + EPSV) * nrm[0].y;
    op[1 * GPTS] = ((acc.y - nrm[1].x) + EPSV) * nrm[1].y;
    op[2 * GPTS] = ((acc.z - nrm[2].x) + EPSV) * nrm[2].y;
    op[3 * GPTS] = ((acc.w - nrm[3].x) + EPSV) * nrm[3].y;
}

extern "C" void kernel_launch(void* const* d_in, const int* in_sizes, int n_in,
                              void* d_out, int out_size, void* d_ws, size_t ws_size,
                              hipStream_t stream) {
    const float* x    = (const float*)d_in[0];
    const int*   tau0 = (const int*)d_in[1];
    float* out = (float*)d_out;
    float2* partials = (float2*)d_ws;    // 8 KiB

    void* args[] = { (void*)&x, (void*)&tau0, (void*)&partials, (void*)&out };
    hipLaunchCooperativeKernel((void*)srp_fused_kernel,
                               dim3(NFG * GSPLIT), dim3(512),
                               args, 0, stream);
}

// Round 6
// 108.364 us; speedup vs baseline: 1.5924x; 1.5924x over previous
//
#include <hip/hip_runtime.h>

#define NPAIR  144
#define KLEN   512
#define GPTS   2048
#define NFRM   256
#define FPB    4                  // frames per gather block
#define NFG    (NFRM / FPB)       // 64 frame groups
#define GSPLIT 4                  // g splits per frame group
#define GPB    (GPTS / GSPLIT)    // 512 g per block (1 per thread)
#define NSLOT  16                 // staged lags: k in {0..7} U {504..511}
#define NJ4    (NPAIR / 4)        // 36 packed-index dwords per g
#define EPSV   1e-12f

// Fused gather: 256 blocks = 64 frame-groups x 4 g-splits, 512 threads
// (1 g x 4 frames each). LDS holds only the lag clumps:
// xc[pair][slot][frame] = 36 KiB.
//
// XCD-locality: blocks dispatch round-robin across the 8 XCDs (XCD = bi%8).
// Encoding fg = bi & 63, gs = bi >> 6 puts the 4 g-split siblings of each
// frame-group (which stage IDENTICAL x-clumps) at bi = fg + {0,64,128,192},
// all congruent mod 8 -> same XCD. Sibling 1 pulls the clump sectors from
// HBM; siblings 2-4 hit that XCD's L2 (~0.6 MB working set vs 4 MB L2).
// Measured R3->R4: 110.2 -> 108.5 us.
//
// tau0 values are geometrically bounded: |lag| <= 0.1m*16000/343 = 4.66,
// so tau in {0..5} U {507..511}; slot = tau & 15 is collision-free on that
// set ({0..5} U {11..15}). We stage 16 slots: seg0 k=0..7 -> slots 0..7,
// seg1 k=504..511 -> slots 8..15 (k & 15 in both cases).
//
// Index prep is fused: during the staging phase (VMEM latency-bound, VALU
// idle) each thread reads its 144 tau0 values (coalesced: lanes vary g)
// and packs 4 pairs' BYTE OFFSETS (slot*16, fits in a byte: max 240) per
// dword, so the gather address is one bfe+add.
//
// NOTE (R5 lesson): do NOT fuse normalization via cooperative grid.sync --
// a 256-block grid.sync costs ~45-50 us on MI355X (cross-XCD spin),
// swamping the ~4 us it saves. Two-kernel split is the right structure.
__global__ __launch_bounds__(512)
void srp_gather_kernel(const float* __restrict__ x,
                       const int* __restrict__ tau0,
                       float* __restrict__ maps) {
    __shared__ __align__(16) float xc[NPAIR * NSLOT * FPB];   // 36864 B

    const int bi = blockIdx.x;
    const int fg = bi & (NFG - 1);          // XCD-locality encoding (see above)
    const int gs = bi >> 6;
    const int t  = threadIdx.x;
    const int g  = gs * GPB + t;

    // Stage clumps: item = (pair, fr, seg), 1152 items x 32 B, ~2.25/thread.
    for (int i = t; i < NPAIR * FPB * 2; i += 512) {
        int pair = i >> 3;
        int fr   = (i >> 1) & 3;
        int seg  = i & 1;
        const float* src = x + ((size_t)(fg * FPB + fr) * NPAIR + pair) * KLEN
                             + (seg ? 504 : 0);
        int base = pair * NSLOT + seg * 8;
        #pragma unroll
        for (int jj = 0; jj < 2; ++jj) {
            float4 v = ((const float4*)src)[jj];
            xc[(base + jj * 4 + 0) * FPB + fr] = v.x;
            xc[(base + jj * 4 + 1) * FPB + fr] = v.y;
            xc[(base + jj * 4 + 2) * FPB + fr] = v.z;
            xc[(base + jj * 4 + 3) * FPB + fr] = v.w;
        }
    }

    // In-register index pack (hidden under staging-load latency + barrier):
    // dj[j4] byte b = (slot << 4) = LDS byte offset within pair's clump row.
    unsigned dj[NJ4];
    #pragma unroll
    for (int j4 = 0; j4 < NJ4; ++j4) {
        unsigned d = 0;
        #pragma unroll
        for (int b = 0; b < 4; ++b) {
            int v = tau0[(j4 * 4 + b) * GPTS + g];   // coalesced (lanes vary g)
            d |= (((unsigned)v & 15u) << 4) << (8 * b);
        }
        dj[j4] = d;
    }

    __syncthreads();

    const char* xb = (const char*)xc;
    float4 acc = {0.f, 0.f, 0.f, 0.f};
    #pragma unroll
    for (int j4 = 0; j4 < NJ4; ++j4) {
        unsigned d = dj[j4];
        #pragma unroll
        for (int b = 0; b < 4; ++b) {
            // byte addr = pair*256 + slot*16 (pair row = 16 slots x 16 B)
            unsigned off = (d >> (8 * b)) & 0xf0u;
            const float4 v = *(const float4*)(xb + (((j4 * 4 + b) << 8) + off));
            acc.x += v.x; acc.y += v.y; acc.z += v.z; acc.w += v.w;
        }
    }

    float* mp = maps + (size_t)(fg * FPB) * GPTS + g;
    mp[0 * GPTS] = acc.x;
    mp[1 * GPTS] = acc.y;
    mp[2 * GPTS] = acc.z;
    mp[3 * GPTS] = acc.w;
}

// One block per frame: zero-mean, then divide by max.
__global__ __launch_bounds__(256)
void srp_norm_kernel(const float* __restrict__ maps, float* __restrict__ out) {
    __shared__ float red[5];
    const int f = blockIdx.x;
    const int t = threadIdx.x;
    const float4* p = (const float4*)(maps + (size_t)f * GPTS);
    float4 s0 = p[t], s1 = p[t + 256];

    const int wave = t >> 6, lane = t & 63;

    float sm = s0.x + s0.y + s0.z + s0.w + s1.x + s1.y + s1.z + s1.w;
    #pragma unroll
    for (int off = 32; off > 0; off >>= 1) sm += __shfl_down(sm, off, 64);
    if (lane == 0) red[wave] = sm;
    __syncthreads();
    if (t == 0) red[4] = (red[0] + red[1] + red[2] + red[3]) * (1.0f / (float)GPTS);
    __syncthreads();
    const float mean = red[4];

    s0.x = s0.x - mean + EPSV; s0.y = s0.y - mean + EPSV;
    s0.z = s0.z - mean + EPSV; s0.w = s0.w - mean + EPSV;
    s1.x = s1.x - mean + EPSV; s1.y = s1.y - mean + EPSV;
    s1.z = s1.z - mean + EPSV; s1.w = s1.w - mean + EPSV;

    float mx = fmaxf(fmaxf(fmaxf(s0.x, s0.y), fmaxf(s0.z, s0.w)),
                     fmaxf(fmaxf(s1.x, s1.y), fmaxf(s1.z, s1.w)));
    #pragma unroll
    for (int off = 32; off > 0; off >>= 1) mx = fmaxf(mx, __shfl_down(mx, off, 64));
    __syncthreads();
    if (lane == 0) red[wave] = mx;
    __syncthreads();
    if (t == 0) red[4] = fmaxf(fmaxf(red[0], red[1]), fmaxf(red[2], red[3]));
    __syncthreads();
    const float inv = 1.0f / red[4];

    float4* o = (float4*)(out + (size_t)f * GPTS);
    o[t]       = make_float4(s0.x * inv, s0.y * inv, s0.z * inv, s0.w * inv);
    o[t + 256] = make_float4(s1.x * inv, s1.y * inv, s1.z * inv, s1.w * inv);
}

extern "C" void kernel_launch(void* const* d_in, const int* in_sizes, int n_in,
                              void* d_out, int out_size, void* d_ws, size_t ws_size,
                              hipStream_t stream) {
    const float* x    = (const float*)d_in[0];
    const int*   tau0 = (const int*)d_in[1];
    float* out = (float*)d_out;

    float* maps = (float*)d_ws;                          // 2 MiB

    srp_gather_kernel<<<NFG * GSPLIT, 512, 0, stream>>>(x, tau0, maps);
    srp_norm_kernel<<<NFRM, 256, 0, stream>>>(maps, out);
}